// Round 14
// baseline (553.700 us; speedup 1.0000x reference)
//
#include <hip/hip_runtime.h>
#include <hip/hip_bf16.h>

#define NN 50000
#define NE 800000
#define NG 500
#define NF 128
#define NH 64
#define SCAN_B ((NN + 255)/256)   // 196

typedef unsigned int u32;
typedef unsigned short u16;
typedef _Float16 h2 __attribute__((ext_vector_type(2)));

__device__ __forceinline__ float bf1(u16 v){ return __uint_as_float(((u32)v) << 16); }

__device__ __forceinline__ float fdot2(h2 a, h2 b, float c){
#if __has_builtin(__builtin_amdgcn_fdot2)
  return __builtin_amdgcn_fdot2(a, b, c, false);
#else
  return c + (float)a.x*(float)b.x + (float)a.y*(float)b.y;
#endif
}
__device__ __forceinline__ u32 pk(float a, float b){
  return __builtin_bit_cast(u32, __builtin_amdgcn_cvt_pkrtz(a, b));
}
__device__ __forceinline__ h2 uph(u32 u){ return __builtin_bit_cast(h2, u); }
__device__ __forceinline__ u16 f16b(float f){ return __builtin_bit_cast(u16, (_Float16)f); }

// decode 8 f16 -> 8 f32
__device__ __forceinline__ void cv8h(uint4 q, float* f){
  h2 v0 = uph(q.x), v1 = uph(q.y), v2 = uph(q.z), v3 = uph(q.w);
  f[0]=(float)v0.x; f[1]=(float)v0.y; f[2]=(float)v1.x; f[3]=(float)v1.y;
  f[4]=(float)v2.x; f[5]=(float)v2.y; f[6]=(float)v3.x; f[7]=(float)v3.y;
}

// ---- dtype probe (f32 inputs proven; kept as output-format hedge)
__global__ void k_detect(const u32* __restrict__ x, int* __restrict__ flag){
  int lane = threadIdx.x;
  u32 w = x[lane];
  u32 lo = w & 0xFFFFu;
  u32 e = (lo >> 7) & 0xFFu;
  bool vote = (e >= 0x60u && e <= 0x8Fu);
  unsigned long long m = __ballot(vote);
  if (lane == 0) flag[0] = (__popcll(m) >= 32) ? 1 : 0;
}

// ---- graph boundaries
__global__ void k_bounds(const int* __restrict__ batch, int* __restrict__ starts){
  int g = threadIdx.x;
  if (g > NG) return;
  int lo = 0, hi = NN;
  while (lo < hi){ int mid = (lo + hi) >> 1; if (batch[mid] < g) lo = mid + 1; else hi = mid; }
  starts[g] = lo;
}

// ---- CSR build: degree count
__global__ __launch_bounds__(256) void k_count(const int* __restrict__ ei, int* __restrict__ deg){
  int e = blockIdx.x*256 + threadIdx.x;
  if (e >= NE) return;
  atomicAdd(&deg[ei[NE + e]], 1);
}

// ---- hierarchical coalesced scan (3 phases)
__global__ __launch_bounds__(256) void k_scanA(const int* __restrict__ deg, int* __restrict__ bsum){
  __shared__ int red[256];
  int t = threadIdx.x;
  int i = blockIdx.x*256 + t;
  red[t] = (i < NN) ? deg[i] : 0;
  __syncthreads();
  for (int off = 128; off > 0; off >>= 1){
    if (t < off) red[t] += red[t+off];
    __syncthreads();
  }
  if (t == 0) bsum[blockIdx.x] = red[0];
}

__global__ __launch_bounds__(256) void k_scanB(int* __restrict__ bsum){
  __shared__ int part[256];
  int t = threadIdx.x;
  int v = (t < SCAN_B) ? bsum[t] : 0;
  part[t] = v;
  __syncthreads();
  for (int off = 1; off < 256; off <<= 1){
    int u = (t >= off) ? part[t-off] : 0;
    __syncthreads();
    part[t] += u;
    __syncthreads();
  }
  if (t < SCAN_B) bsum[t] = part[t] - v;   // exclusive
}

__global__ __launch_bounds__(256) void k_scanC(const int* __restrict__ deg, const int* __restrict__ bsum,
    int* __restrict__ rowptr, int* __restrict__ cursor){
  __shared__ int part[256];
  int t = threadIdx.x;
  int i = blockIdx.x*256 + t;
  int v = (i < NN) ? deg[i] : 0;
  part[t] = v;
  __syncthreads();
  for (int off = 1; off < 256; off <<= 1){
    int u = (t >= off) ? part[t-off] : 0;
    __syncthreads();
    part[t] += u;
    __syncthreads();
  }
  int ex = part[t] - v + bsum[blockIdx.x];
  if (i < NN){ rowptr[i] = ex; cursor[i] = ex; }
  if (blockIdx.x == 0 && t == 0) rowptr[NN] = NE;
}

// ---- CSR fill: 4 edges/thread (independent atomic->scatter chains, coalesced passes)
#define FILL_T ((NE + 4*256 - 1) / (4*256))   // 782 blocks
__global__ __launch_bounds__(256) void k_fill(const int* __restrict__ ei,
    int* __restrict__ cursor, int* __restrict__ csr){
  int base = blockIdx.x*256 + threadIdx.x;
  const int stride = FILL_T*256;
  #pragma unroll
  for (int k = 0; k < 4; k++){
    int e = base + k*stride;
    if (e < NE){
      int dst = ei[NE + e];
      int slot = atomicAdd(&cursor[dst], 1);
      csr[slot] = ei[e];
    }
  }
}

// ---- gather (f16 h): 16 edge-slots x 4 column-chunks; block 0 re-zeros s1/s2
__global__ __launch_bounds__(256) void k_gather(const u16* __restrict__ h,
    const int* __restrict__ rowptr, const int* __restrict__ csr, float* __restrict__ U,
    float* __restrict__ s1){
  if (blockIdx.x == 0 && threadIdx.x < 128) s1[threadIdx.x] = 0.f;  // s1[0:64], s2[64:128]
  int wid = threadIdx.x >> 6, lane = threadIdx.x & 63;
  int node = blockIdx.x*4 + wid;
  if (node >= NN) return;
  int chunk = lane & 3, epar = lane >> 2;    // 4 chunks x 16 slots
  int beg = rowptr[node], en = rowptr[node+1];
  float acc[16];
  #pragma unroll
  for (int i = 0; i < 16; i++) acc[i] = 0.f;
  if (epar == 0){
    const uint4* p = (const uint4*)&h[(size_t)node*NH + chunk*16];
    cv8h(p[0], &acc[0]);
    cv8h(p[1], &acc[8]);
  }
  for (int j = beg + epar; j < en; j += 16){
    int src = csr[j];
    const uint4* p = (const uint4*)&h[(size_t)src*NH + chunk*16];
    uint4 q0 = p[0], q1 = p[1];
    float f[16];
    cv8h(q0, &f[0]);
    cv8h(q1, &f[8]);
    #pragma unroll
    for (int i = 0; i < 16; i++) acc[i] += f[i];
  }
  #pragma unroll
  for (int i = 0; i < 16; i++){
    acc[i] += __shfl_xor(acc[i], 4);
    acc[i] += __shfl_xor(acc[i], 8);
    acc[i] += __shfl_xor(acc[i], 16);
    acc[i] += __shfl_xor(acc[i], 32);
  }
  if (epar == 0){
    float* dst = &U[(size_t)node*NH + chunk*16];
    #pragma unroll
    for (int q4 = 0; q4 < 4; q4++){
      float4 v; v.x=acc[q4*4]; v.y=acc[q4*4+1]; v.z=acc[q4*4+2]; v.w=acc[q4*4+3];
      *(float4*)&dst[q4*4] = v;
    }
  }
}

// ---- transform: LDS-staged x + 16-reg weight hoist (R13-proven)
__global__ __launch_bounds__(256) void k_transform_f(const float* __restrict__ x,
    const float* __restrict__ Wt, const float* __restrict__ bt,
    float* __restrict__ t, float* __restrict__ s1, float* __restrict__ s2){
  __shared__ u32 sWh[64*64];      // 16 KB: half2(W[2k2][c], W[2k2+1][c]) at [k2][c]
  __shared__ u32 sXh[32*64];      // 8 KB: half2(x[r][2k2], x[r][2k2+1]) at [r][k2]
  __shared__ float sRed[8*NH];
  int tid = threadIdx.x;
  for (int i = tid; i < 1024; i += 256){
    int k2 = i >> 4, c4 = i & 15;
    float4 a = *(const float4*)(Wt + (size_t)(2*k2)*NH + c4*4);
    float4 b = *(const float4*)(Wt + (size_t)(2*k2+1)*NH + c4*4);
    uint4 st;
    st.x = pk(a.x, b.x); st.y = pk(a.y, b.y); st.z = pk(a.z, b.z); st.w = pk(a.w, b.w);
    *(uint4*)&sWh[k2*64 + c4*4] = st;
  }
  int row0 = blockIdx.x*32;
  for (int i = tid; i < 2048; i += 256){
    int r = i >> 6, k2 = i & 63;
    int row = row0 + r;
    float2 v;
    if (row < NN) v = *(const float2*)(x + (size_t)row*NF + 2*k2);
    else { v.x = 0.f; v.y = 0.f; }
    sXh[r*64 + k2] = pk(v.x, v.y);
  }
  __syncthreads();
  int tx = tid & 63, ty = tid >> 6;
  float b = bt[tx];
  float acc0[8], acc1[8];
  #pragma unroll
  for (int i = 0; i < 8; i++){ acc0[i] = 0.f; acc1[i] = 0.f; }
  #pragma unroll 1
  for (int ch = 0; ch < 4; ch++){        // 16 k2 per chunk: only 16 wreg live
    u32 wreg[16];
    #pragma unroll
    for (int j = 0; j < 16; j++) wreg[j] = sWh[(ch*16+j)*64 + tx];
    #pragma unroll
    for (int i = 0; i < 8; i++){
      int r = ty*8 + i;
      const uint4* xp = (const uint4*)&sXh[r*64 + ch*16];   // uniform b128 (4 k2 each)
      #pragma unroll
      for (int q = 0; q < 4; q++){
        uint4 xv = xp[q];
        acc0[i] = fdot2(uph(xv.x), uph(wreg[q*4+0]), acc0[i]);
        acc1[i] = fdot2(uph(xv.y), uph(wreg[q*4+1]), acc1[i]);
        acc0[i] = fdot2(uph(xv.z), uph(wreg[q*4+2]), acc0[i]);
        acc1[i] = fdot2(uph(xv.w), uph(wreg[q*4+3]), acc1[i]);
      }
    }
  }
  float ls1 = 0.f, ls2 = 0.f;
  #pragma unroll
  for (int i = 0; i < 8; i++){
    int row = row0 + ty*8 + i;
    float acc = acc0[i] + acc1[i] + b;
    if (row < NN){
      t[(size_t)row*NH + tx] = acc;
      ls1 += acc; ls2 += acc*acc;
    }
  }
  sRed[ty*NH + tx] = ls1;
  sRed[(4+ty)*NH + tx] = ls2;
  __syncthreads();
  if (ty == 0){
    float a1 = sRed[tx] + sRed[NH+tx] + sRed[2*NH+tx] + sRed[3*NH+tx];
    float a2 = sRed[4*NH+tx] + sRed[5*NH+tx] + sRed[6*NH+tx] + sRed[7*NH+tx];
    unsafeAtomicAdd(&s1[tx], a1);
    unsafeAtomicAdd(&s2[tx], a2);
  }
}

// ---- per-graph embed with fused BN-fold; writes h as f16 (gather is sole consumer)
__global__ __launch_bounds__(256) void k_embed(const float* __restrict__ t,
    const float* __restrict__ s1, const float* __restrict__ s2,
    const void* __restrict__ gamma, const void* __restrict__ beta, int ofs,
    u16* __restrict__ h, int write_h,
    const int* __restrict__ starts, const int* __restrict__ flag,
    void* __restrict__ dout, int layer){
  __shared__ float sRed[8*NH];
  int g = blockIdx.x;
  int tx = threadIdx.x & 63, ty = threadIdx.x >> 6;
  int bf = flag[0];
  float gm = bf ? bf1(((const u16*)gamma)[ofs+tx]) : ((const float*)gamma)[ofs+tx];
  float be = bf ? bf1(((const u16*)beta)[ofs+tx])  : ((const float*)beta)[ofs+tx];
  float mean = s1[tx] * (1.f/NN);
  float var  = s2[tx] * (1.f/NN) - mean*mean;
  float rr = rsqrtf(fmaxf(var, 0.f) + 1e-5f);
  float sc = gm * rr;
  float sh = be - mean*sc;
  int st = starts[g], en = starts[g+1];
  float ls1 = 0.f, ls2 = 0.f;
  if (write_h){
    for (int n = st + ty; n < en; n += 4){
      float z = t[(size_t)n*NH + tx] * sc + sh;
      h[(size_t)n*NH + tx] = f16b(z);
      ls1 += z; ls2 += z*z;
    }
  } else {
    for (int n = st + ty; n < en; n += 4){
      float z = t[(size_t)n*NH + tx] * sc + sh;
      ls1 += z; ls2 += z*z;
    }
  }
  sRed[ty*NH + tx] = ls1;
  sRed[(4+ty)*NH + tx] = ls2;
  __syncthreads();
  if (ty == 0){
    float a1 = sRed[tx] + sRed[NH+tx] + sRed[2*NH+tx] + sRed[3*NH+tx];
    float a2 = sRed[4*NH+tx] + sRed[5*NH+tx] + sRed[6*NH+tx] + sRed[7*NH+tx];
    int cnt = en - st;
    float inv = 1.f / (float)max(cnt, 1);
    float m = a1 * inv;
    float vv = a2 * inv - m*m;
    float s = sqrtf(fmaxf(vv, 0.f));
    size_t eidx = ((size_t)layer*NG + g)*NH + tx;
    size_t sidx = (size_t)4*NG*NH + eidx;
    if (bf){
      ((__hip_bfloat16*)dout)[eidx] = __float2bfloat16(m);
      ((__hip_bfloat16*)dout)[sidx] = __float2bfloat16(s);
    } else {
      ((float*)dout)[eidx] = m;
      ((float*)dout)[sidx] = s;
    }
  }
}

// ---- MLP: R11 structure, 32 rows/block for 2x parallelism (1563 blocks, 26 KB LDS)
__global__ __launch_bounds__(256) void k_mlp_f(float* __restrict__ U,
    const float* __restrict__ W1, const float* __restrict__ W2, int wofs,
    float* __restrict__ s1, float* __restrict__ s2){
  __shared__ u32 sW1h[32*64];   // 8 KB
  __shared__ u32 sW2h[32*64];   // 8 KB
  __shared__ u16 sUh[32*64];    // 4 KB
  __shared__ u16 sVh[32*64];    // 4 KB
  __shared__ float sRed[8*NH];  // 2 KB
  int tid = threadIdx.x;
  for (int i = tid; i < 512; i += 256){
    int k2 = i >> 4, c4 = i & 15;
    float4 a1 = *(const float4*)(W1 + wofs + (size_t)(2*k2)*NH + c4*4);
    float4 b1 = *(const float4*)(W1 + wofs + (size_t)(2*k2+1)*NH + c4*4);
    uint4 s;
    s.x = pk(a1.x, b1.x); s.y = pk(a1.y, b1.y); s.z = pk(a1.z, b1.z); s.w = pk(a1.w, b1.w);
    *(uint4*)&sW1h[k2*64 + c4*4] = s;
    float4 a2 = *(const float4*)(W2 + wofs + (size_t)(2*k2)*NH + c4*4);
    float4 b2 = *(const float4*)(W2 + wofs + (size_t)(2*k2+1)*NH + c4*4);
    uint4 s2v;
    s2v.x = pk(a2.x, b2.x); s2v.y = pk(a2.y, b2.y); s2v.z = pk(a2.z, b2.z); s2v.w = pk(a2.w, b2.w);
    *(uint4*)&sW2h[k2*64 + c4*4] = s2v;
  }
  int node0 = blockIdx.x*32;
  int nrows = min(32, NN - node0);
  for (int i = tid; i < 512; i += 256){
    int r = i >> 4, c4 = i & 15;
    float4 q;
    if (r < nrows) q = *(const float4*)&U[(size_t)(node0+r)*NH + c4*4];
    else { q.x=0.f; q.y=0.f; q.z=0.f; q.w=0.f; }
    uint2 w; w.x = pk(q.x, q.y); w.y = pk(q.z, q.w);
    *(uint2*)&sUh[r*64 + c4*4] = w;
  }
  __syncthreads();
  int tx = tid & 63, ty = tid >> 6;
  // phase A: V = relu(U @ W1); wave owns 8 rows, paired (ra, ra+4)
  for (int i = 0; i < 4; i++){
    int ra = ty*8 + i, rb = ra + 4;
    float acca = 0.f, accb = 0.f;
    #pragma unroll
    for (int k8 = 0; k8 < 8; k8++){
      uint4 ua = *(const uint4*)&sUh[ra*64 + k8*8];
      uint4 ub = *(const uint4*)&sUh[rb*64 + k8*8];
      h2 w0 = uph(sW1h[(k8*4+0)*64 + tx]);
      h2 w1 = uph(sW1h[(k8*4+1)*64 + tx]);
      h2 w2 = uph(sW1h[(k8*4+2)*64 + tx]);
      h2 w3 = uph(sW1h[(k8*4+3)*64 + tx]);
      acca = fdot2(uph(ua.x), w0, acca); accb = fdot2(uph(ub.x), w0, accb);
      acca = fdot2(uph(ua.y), w1, acca); accb = fdot2(uph(ub.y), w1, accb);
      acca = fdot2(uph(ua.z), w2, acca); accb = fdot2(uph(ub.z), w2, accb);
      acca = fdot2(uph(ua.w), w3, acca); accb = fdot2(uph(ub.w), w3, accb);
    }
    sVh[ra*64 + tx] = f16b(fmaxf(acca, 0.f));
    sVh[rb*64 + tx] = f16b(fmaxf(accb, 0.f));
  }
  __syncthreads();
  // phase B: T = relu(V @ W2), in-place to U
  float ls1 = 0.f, ls2 = 0.f;
  for (int i = 0; i < 4; i++){
    int ra = ty*8 + i, rb = ra + 4;
    float acca = 0.f, accb = 0.f;
    #pragma unroll
    for (int k8 = 0; k8 < 8; k8++){
      uint4 va = *(const uint4*)&sVh[ra*64 + k8*8];
      uint4 vb = *(const uint4*)&sVh[rb*64 + k8*8];
      h2 w0 = uph(sW2h[(k8*4+0)*64 + tx]);
      h2 w1 = uph(sW2h[(k8*4+1)*64 + tx]);
      h2 w2 = uph(sW2h[(k8*4+2)*64 + tx]);
      h2 w3 = uph(sW2h[(k8*4+3)*64 + tx]);
      acca = fdot2(uph(va.x), w0, acca); accb = fdot2(uph(vb.x), w0, accb);
      acca = fdot2(uph(va.y), w1, acca); accb = fdot2(uph(vb.y), w1, accb);
      acca = fdot2(uph(va.z), w2, acca); accb = fdot2(uph(vb.z), w2, accb);
      acca = fdot2(uph(va.w), w3, acca); accb = fdot2(uph(vb.w), w3, accb);
    }
    float ta = fmaxf(acca, 0.f), tb = fmaxf(accb, 0.f);
    if (ra < nrows){ U[(size_t)(node0+ra)*NH + tx] = ta; ls1 += ta; ls2 += ta*ta; }
    if (rb < nrows){ U[(size_t)(node0+rb)*NH + tx] = tb; ls1 += tb; ls2 += tb*tb; }
  }
  __syncthreads();
  sRed[ty*NH + tx] = ls1;
  sRed[(4+ty)*NH + tx] = ls2;
  __syncthreads();
  if (ty == 0){
    float a1 = sRed[tx] + sRed[NH+tx] + sRed[2*NH+tx] + sRed[3*NH+tx];
    float a2 = sRed[4*NH+tx] + sRed[5*NH+tx] + sRed[6*NH+tx] + sRed[7*NH+tx];
    unsafeAtomicAdd(&s1[tx], a1);
    unsafeAtomicAdd(&s2[tx], a2);
  }
}

extern "C" void kernel_launch(void* const* d_in, const int* in_sizes, int n_in,
                              void* d_out, int out_size, void* d_ws, size_t ws_size,
                              hipStream_t stream) {
  const void* x    = d_in[0];
  const int* ei    = (const int*)d_in[1];
  const int* batch = (const int*)d_in[2];
  const void* Wt   = d_in[3];
  const void* bt   = d_in[4];
  const void* g0   = d_in[5];
  const void* b0   = d_in[6];
  const void* W1   = d_in[7];
  const void* W2   = d_in[8];
  const void* gs   = d_in[9];
  const void* bs   = d_in[10];

  u16*  hbuf = (u16*)d_ws;                      // NN*NH f16 (in NN*NH*4-byte slot)
  float* ubuf = (float*)d_ws + (size_t)NN*NH;   // NN*NH f32 (U, then in-place T)
  float* s1   = ubuf + (size_t)NN*NH;           // 64
  float* s2   = s1 + NH;                        // 64 (contiguous after s1)
  float* pad  = s2 + NH;                        // 128 (layout spacer)
  int* starts = (int*)(pad + 2*NH);             // 512
  int* flag   = starts + 512;                   // 64 (padded)
  int* deg    = flag + 64;                      // NN
  int* rowptr = deg + NN;                       // NN+64
  int* cursor = rowptr + NN + 64;               // NN
  int* csr    = cursor + NN;                    // NE
  int* bsum   = csr + NE;                       // 256

  hipMemsetAsync(s1, 0, 2*NH*sizeof(float), stream);
  hipMemsetAsync(deg, 0, NN*sizeof(int), stream);
  k_detect<<<1, 64, 0, stream>>>((const u32*)x, flag);
  k_bounds<<<1, 512, 0, stream>>>(batch, starts);
  k_count<<<(NE+255)/256, 256, 0, stream>>>(ei, deg);
  k_scanA<<<SCAN_B, 256, 0, stream>>>(deg, bsum);
  k_scanB<<<1, 256, 0, stream>>>(bsum);
  k_scanC<<<SCAN_B, 256, 0, stream>>>(deg, bsum, rowptr, cursor);
  k_fill<<<FILL_T, 256, 0, stream>>>(ei, cursor, csr);

  k_transform_f<<<(NN+31)/32, 256, 0, stream>>>((const float*)x, (const float*)Wt, (const float*)bt, ubuf, s1, s2);
  k_embed<<<NG, 256, 0, stream>>>(ubuf, s1, s2, g0, b0, 0, hbuf, 1, starts, flag, d_out, 0);

  for (int l = 0; l < 3; l++){
    k_gather<<<(NN+3)/4, 256, 0, stream>>>(hbuf, rowptr, csr, ubuf, s1);  // also zeros s1/s2
    k_mlp_f<<<(NN+31)/32, 256, 0, stream>>>(ubuf, (const float*)W1, (const float*)W2, l*NH*NH, s1, s2);
    k_embed<<<NG, 256, 0, stream>>>(ubuf, s1, s2, gs, bs, l*NH, hbuf, (l < 2) ? 1 : 0, starts, flag, d_out, l+1);
  }
}

// Round 15
// 444.539 us; speedup vs baseline: 1.2456x; 1.2456x over previous
//
#include <hip/hip_runtime.h>
#include <hip/hip_bf16.h>

#define NN 50000
#define NE 800000
#define NG 500
#define NF 128
#define NH 64
#define SCAN_B ((NN + 255)/256)   // 196

typedef unsigned int u32;
typedef unsigned short u16;
typedef _Float16 h2 __attribute__((ext_vector_type(2)));

__device__ __forceinline__ float bf1(u16 v){ return __uint_as_float(((u32)v) << 16); }

__device__ __forceinline__ float fdot2(h2 a, h2 b, float c){
#if __has_builtin(__builtin_amdgcn_fdot2)
  return __builtin_amdgcn_fdot2(a, b, c, false);
#else
  return c + (float)a.x*(float)b.x + (float)a.y*(float)b.y;
#endif
}
__device__ __forceinline__ u32 pk(float a, float b){
  return __builtin_bit_cast(u32, __builtin_amdgcn_cvt_pkrtz(a, b));
}
__device__ __forceinline__ h2 uph(u32 u){ return __builtin_bit_cast(h2, u); }
__device__ __forceinline__ u16 f16b(float f){ return __builtin_bit_cast(u16, (_Float16)f); }

// decode 8 f16 -> 8 f32
__device__ __forceinline__ void cv8h(uint4 q, float* f){
  h2 v0 = uph(q.x), v1 = uph(q.y), v2 = uph(q.z), v3 = uph(q.w);
  f[0]=(float)v0.x; f[1]=(float)v0.y; f[2]=(float)v1.x; f[3]=(float)v1.y;
  f[4]=(float)v2.x; f[5]=(float)v2.y; f[6]=(float)v3.x; f[7]=(float)v3.y;
}

// ---- dtype probe (f32 inputs proven; kept as output-format hedge)
__global__ void k_detect(const u32* __restrict__ x, int* __restrict__ flag){
  int lane = threadIdx.x;
  u32 w = x[lane];
  u32 lo = w & 0xFFFFu;
  u32 e = (lo >> 7) & 0xFFu;
  bool vote = (e >= 0x60u && e <= 0x8Fu);
  unsigned long long m = __ballot(vote);
  if (lane == 0) flag[0] = (__popcll(m) >= 32) ? 1 : 0;
}

// ---- graph boundaries
__global__ void k_bounds(const int* __restrict__ batch, int* __restrict__ starts){
  int g = threadIdx.x;
  if (g > NG) return;
  int lo = 0, hi = NN;
  while (lo < hi){ int mid = (lo + hi) >> 1; if (batch[mid] < g) lo = mid + 1; else hi = mid; }
  starts[g] = lo;
}

// ---- CSR build: degree count
__global__ __launch_bounds__(256) void k_count(const int* __restrict__ ei, int* __restrict__ deg){
  int e = blockIdx.x*256 + threadIdx.x;
  if (e >= NE) return;
  atomicAdd(&deg[ei[NE + e]], 1);
}

// ---- hierarchical coalesced scan (3 phases)
__global__ __launch_bounds__(256) void k_scanA(const int* __restrict__ deg, int* __restrict__ bsum){
  __shared__ int red[256];
  int t = threadIdx.x;
  int i = blockIdx.x*256 + t;
  red[t] = (i < NN) ? deg[i] : 0;
  __syncthreads();
  for (int off = 128; off > 0; off >>= 1){
    if (t < off) red[t] += red[t+off];
    __syncthreads();
  }
  if (t == 0) bsum[blockIdx.x] = red[0];
}

__global__ __launch_bounds__(256) void k_scanB(int* __restrict__ bsum){
  __shared__ int part[256];
  int t = threadIdx.x;
  int v = (t < SCAN_B) ? bsum[t] : 0;
  part[t] = v;
  __syncthreads();
  for (int off = 1; off < 256; off <<= 1){
    int u = (t >= off) ? part[t-off] : 0;
    __syncthreads();
    part[t] += u;
    __syncthreads();
  }
  if (t < SCAN_B) bsum[t] = part[t] - v;   // exclusive
}

__global__ __launch_bounds__(256) void k_scanC(const int* __restrict__ deg, const int* __restrict__ bsum,
    int* __restrict__ rowptr, int* __restrict__ cursor){
  __shared__ int part[256];
  int t = threadIdx.x;
  int i = blockIdx.x*256 + t;
  int v = (i < NN) ? deg[i] : 0;
  part[t] = v;
  __syncthreads();
  for (int off = 1; off < 256; off <<= 1){
    int u = (t >= off) ? part[t-off] : 0;
    __syncthreads();
    part[t] += u;
    __syncthreads();
  }
  int ex = part[t] - v + bsum[blockIdx.x];
  if (i < NN){ rowptr[i] = ex; cursor[i] = ex; }
  if (blockIdx.x == 0 && t == 0) rowptr[NN] = NE;
}

// ---- CSR fill (R13-proven: 1 edge/thread)
__global__ __launch_bounds__(256) void k_fill(const int* __restrict__ ei,
    int* __restrict__ cursor, int* __restrict__ csr){
  int e = blockIdx.x*256 + threadIdx.x;
  if (e >= NE) return;
  int dst = ei[NE + e];
  int slot = atomicAdd(&cursor[dst], 1);
  csr[slot] = ei[e];
}

// ---- gather (f16 h): R13 8-slot x 8-chunk layout + edge-loop unroll x2 (ILP)
__global__ __launch_bounds__(256) void k_gather(const u16* __restrict__ h,
    const int* __restrict__ rowptr, const int* __restrict__ csr, float* __restrict__ U,
    float* __restrict__ s1){
  if (blockIdx.x == 0 && threadIdx.x < 128) s1[threadIdx.x] = 0.f;  // s1[0:64], s2[64:128]
  int wid = threadIdx.x >> 6, lane = threadIdx.x & 63;
  int node = blockIdx.x*4 + wid;
  if (node >= NN) return;
  int chunk = lane & 7, epar = lane >> 3;
  int beg = rowptr[node], en = rowptr[node+1];
  float acc[8] = {0.f,0.f,0.f,0.f,0.f,0.f,0.f,0.f};
  if (epar == 0){
    uint4 q = *(const uint4*)&h[(size_t)node*NH + chunk*8];
    cv8h(q, acc);
  }
  int j = beg + epar;
  for (; j + 8 < en; j += 16){            // 2 edges in flight per lane
    int src0 = csr[j];
    int src1 = csr[j+8];
    uint4 q0 = *(const uint4*)&h[(size_t)src0*NH + chunk*8];
    uint4 q1 = *(const uint4*)&h[(size_t)src1*NH + chunk*8];
    float f0[8], f1[8];
    cv8h(q0, f0);
    cv8h(q1, f1);
    #pragma unroll
    for (int i = 0; i < 8; i++) acc[i] += f0[i] + f1[i];
  }
  if (j < en){
    int src = csr[j];
    uint4 q = *(const uint4*)&h[(size_t)src*NH + chunk*8];
    float f[8]; cv8h(q, f);
    #pragma unroll
    for (int i = 0; i < 8; i++) acc[i] += f[i];
  }
  #pragma unroll
  for (int i = 0; i < 8; i++){
    acc[i] += __shfl_xor(acc[i], 8);
    acc[i] += __shfl_xor(acc[i], 16);
    acc[i] += __shfl_xor(acc[i], 32);
  }
  if (epar == 0){
    float* dst = &U[(size_t)node*NH + chunk*8];
    float4 v0; v0.x=acc[0]; v0.y=acc[1]; v0.z=acc[2]; v0.w=acc[3];
    float4 v1; v1.x=acc[4]; v1.y=acc[5]; v1.z=acc[6]; v1.w=acc[7];
    *(float4*)&dst[0] = v0;
    *(float4*)&dst[4] = v1;
  }
}

// ---- transform: LDS-staged x + 16-reg weight hoist (R13-proven)
__global__ __launch_bounds__(256) void k_transform_f(const float* __restrict__ x,
    const float* __restrict__ Wt, const float* __restrict__ bt,
    float* __restrict__ t, float* __restrict__ s1, float* __restrict__ s2){
  __shared__ u32 sWh[64*64];      // 16 KB: half2(W[2k2][c], W[2k2+1][c]) at [k2][c]
  __shared__ u32 sXh[32*64];      // 8 KB: half2(x[r][2k2], x[r][2k2+1]) at [r][k2]
  __shared__ float sRed[8*NH];
  int tid = threadIdx.x;
  for (int i = tid; i < 1024; i += 256){
    int k2 = i >> 4, c4 = i & 15;
    float4 a = *(const float4*)(Wt + (size_t)(2*k2)*NH + c4*4);
    float4 b = *(const float4*)(Wt + (size_t)(2*k2+1)*NH + c4*4);
    uint4 st;
    st.x = pk(a.x, b.x); st.y = pk(a.y, b.y); st.z = pk(a.z, b.z); st.w = pk(a.w, b.w);
    *(uint4*)&sWh[k2*64 + c4*4] = st;
  }
  int row0 = blockIdx.x*32;
  for (int i = tid; i < 2048; i += 256){
    int r = i >> 6, k2 = i & 63;
    int row = row0 + r;
    float2 v;
    if (row < NN) v = *(const float2*)(x + (size_t)row*NF + 2*k2);
    else { v.x = 0.f; v.y = 0.f; }
    sXh[r*64 + k2] = pk(v.x, v.y);
  }
  __syncthreads();
  int tx = tid & 63, ty = tid >> 6;
  float b = bt[tx];
  float acc0[8], acc1[8];
  #pragma unroll
  for (int i = 0; i < 8; i++){ acc0[i] = 0.f; acc1[i] = 0.f; }
  #pragma unroll 1
  for (int ch = 0; ch < 4; ch++){        // 16 k2 per chunk: only 16 wreg live
    u32 wreg[16];
    #pragma unroll
    for (int j = 0; j < 16; j++) wreg[j] = sWh[(ch*16+j)*64 + tx];
    #pragma unroll
    for (int i = 0; i < 8; i++){
      int r = ty*8 + i;
      const uint4* xp = (const uint4*)&sXh[r*64 + ch*16];   // uniform b128 (4 k2 each)
      #pragma unroll
      for (int q = 0; q < 4; q++){
        uint4 xv = xp[q];
        acc0[i] = fdot2(uph(xv.x), uph(wreg[q*4+0]), acc0[i]);
        acc1[i] = fdot2(uph(xv.y), uph(wreg[q*4+1]), acc1[i]);
        acc0[i] = fdot2(uph(xv.z), uph(wreg[q*4+2]), acc0[i]);
        acc1[i] = fdot2(uph(xv.w), uph(wreg[q*4+3]), acc1[i]);
      }
    }
  }
  float ls1 = 0.f, ls2 = 0.f;
  #pragma unroll
  for (int i = 0; i < 8; i++){
    int row = row0 + ty*8 + i;
    float acc = acc0[i] + acc1[i] + b;
    if (row < NN){
      t[(size_t)row*NH + tx] = acc;
      ls1 += acc; ls2 += acc*acc;
    }
  }
  sRed[ty*NH + tx] = ls1;
  sRed[(4+ty)*NH + tx] = ls2;
  __syncthreads();
  if (ty == 0){
    float a1 = sRed[tx] + sRed[NH+tx] + sRed[2*NH+tx] + sRed[3*NH+tx];
    float a2 = sRed[4*NH+tx] + sRed[5*NH+tx] + sRed[6*NH+tx] + sRed[7*NH+tx];
    unsafeAtomicAdd(&s1[tx], a1);
    unsafeAtomicAdd(&s2[tx], a2);
  }
}

// ---- per-graph embed with fused BN-fold; writes h as f16 (gather is sole consumer)
__global__ __launch_bounds__(256) void k_embed(const float* __restrict__ t,
    const float* __restrict__ s1, const float* __restrict__ s2,
    const void* __restrict__ gamma, const void* __restrict__ beta, int ofs,
    u16* __restrict__ h, int write_h,
    const int* __restrict__ starts, const int* __restrict__ flag,
    void* __restrict__ dout, int layer){
  __shared__ float sRed[8*NH];
  int g = blockIdx.x;
  int tx = threadIdx.x & 63, ty = threadIdx.x >> 6;
  int bf = flag[0];
  float gm = bf ? bf1(((const u16*)gamma)[ofs+tx]) : ((const float*)gamma)[ofs+tx];
  float be = bf ? bf1(((const u16*)beta)[ofs+tx])  : ((const float*)beta)[ofs+tx];
  float mean = s1[tx] * (1.f/NN);
  float var  = s2[tx] * (1.f/NN) - mean*mean;
  float rr = rsqrtf(fmaxf(var, 0.f) + 1e-5f);
  float sc = gm * rr;
  float sh = be - mean*sc;
  int st = starts[g], en = starts[g+1];
  float ls1 = 0.f, ls2 = 0.f;
  if (write_h){
    for (int n = st + ty; n < en; n += 4){
      float z = t[(size_t)n*NH + tx] * sc + sh;
      h[(size_t)n*NH + tx] = f16b(z);
      ls1 += z; ls2 += z*z;
    }
  } else {
    for (int n = st + ty; n < en; n += 4){
      float z = t[(size_t)n*NH + tx] * sc + sh;
      ls1 += z; ls2 += z*z;
    }
  }
  sRed[ty*NH + tx] = ls1;
  sRed[(4+ty)*NH + tx] = ls2;
  __syncthreads();
  if (ty == 0){
    float a1 = sRed[tx] + sRed[NH+tx] + sRed[2*NH+tx] + sRed[3*NH+tx];
    float a2 = sRed[4*NH+tx] + sRed[5*NH+tx] + sRed[6*NH+tx] + sRed[7*NH+tx];
    int cnt = en - st;
    float inv = 1.f / (float)max(cnt, 1);
    float m = a1 * inv;
    float vv = a2 * inv - m*m;
    float s = sqrtf(fmaxf(vv, 0.f));
    size_t eidx = ((size_t)layer*NG + g)*NH + tx;
    size_t sidx = (size_t)4*NG*NH + eidx;
    if (bf){
      ((__hip_bfloat16*)dout)[eidx] = __float2bfloat16(m);
      ((__hip_bfloat16*)dout)[sidx] = __float2bfloat16(s);
    } else {
      ((float*)dout)[eidx] = m;
      ((float*)dout)[sidx] = s;
    }
  }
}

// ---- MLP: R13-proven (64 rows/block, f16 staging + LDS weight reads + fdot2, row-paired)
__global__ __launch_bounds__(256) void k_mlp_f(float* __restrict__ U,
    const float* __restrict__ W1, const float* __restrict__ W2, int wofs,
    float* __restrict__ s1, float* __restrict__ s2){
  __shared__ u32 sW1h[32*64];   // 8 KB
  __shared__ u32 sW2h[32*64];   // 8 KB
  __shared__ u16 sUh[64*64];    // 8 KB
  __shared__ u16 sVh[64*64];    // 8 KB
  __shared__ float sRed[8*NH];  // 2 KB
  int tid = threadIdx.x;
  for (int i = tid; i < 512; i += 256){
    int k2 = i >> 4, c4 = i & 15;
    float4 a1 = *(const float4*)(W1 + wofs + (size_t)(2*k2)*NH + c4*4);
    float4 b1 = *(const float4*)(W1 + wofs + (size_t)(2*k2+1)*NH + c4*4);
    uint4 s;
    s.x = pk(a1.x, b1.x); s.y = pk(a1.y, b1.y); s.z = pk(a1.z, b1.z); s.w = pk(a1.w, b1.w);
    *(uint4*)&sW1h[k2*64 + c4*4] = s;
    float4 a2 = *(const float4*)(W2 + wofs + (size_t)(2*k2)*NH + c4*4);
    float4 b2 = *(const float4*)(W2 + wofs + (size_t)(2*k2+1)*NH + c4*4);
    uint4 s2v;
    s2v.x = pk(a2.x, b2.x); s2v.y = pk(a2.y, b2.y); s2v.z = pk(a2.z, b2.z); s2v.w = pk(a2.w, b2.w);
    *(uint4*)&sW2h[k2*64 + c4*4] = s2v;
  }
  int node0 = blockIdx.x*64;
  int nrows = min(64, NN - node0);
  for (int i = tid; i < 1024; i += 256){
    int r = i >> 4, c4 = i & 15;
    float4 q;
    if (r < nrows) q = *(const float4*)&U[(size_t)(node0+r)*NH + c4*4];
    else { q.x=0.f; q.y=0.f; q.z=0.f; q.w=0.f; }
    uint2 w; w.x = pk(q.x, q.y); w.y = pk(q.z, q.w);
    *(uint2*)&sUh[r*64 + c4*4] = w;
  }
  __syncthreads();
  int tx = tid & 63, ty = tid >> 6;
  // phase A: V = relu(U @ W1)
  for (int i = 0; i < 8; i++){
    int ra = ty*16 + i, rb = ra + 8;
    float acca = 0.f, accb = 0.f;
    #pragma unroll
    for (int k8 = 0; k8 < 8; k8++){
      uint4 ua = *(const uint4*)&sUh[ra*64 + k8*8];
      uint4 ub = *(const uint4*)&sUh[rb*64 + k8*8];
      h2 w0 = uph(sW1h[(k8*4+0)*64 + tx]);
      h2 w1 = uph(sW1h[(k8*4+1)*64 + tx]);
      h2 w2 = uph(sW1h[(k8*4+2)*64 + tx]);
      h2 w3 = uph(sW1h[(k8*4+3)*64 + tx]);
      acca = fdot2(uph(ua.x), w0, acca); accb = fdot2(uph(ub.x), w0, accb);
      acca = fdot2(uph(ua.y), w1, acca); accb = fdot2(uph(ub.y), w1, accb);
      acca = fdot2(uph(ua.z), w2, acca); accb = fdot2(uph(ub.z), w2, accb);
      acca = fdot2(uph(ua.w), w3, acca); accb = fdot2(uph(ub.w), w3, accb);
    }
    sVh[ra*64 + tx] = f16b(fmaxf(acca, 0.f));
    sVh[rb*64 + tx] = f16b(fmaxf(accb, 0.f));
  }
  __syncthreads();
  // phase B: T = relu(V @ W2), in-place to U
  float ls1 = 0.f, ls2 = 0.f;
  for (int i = 0; i < 8; i++){
    int ra = ty*16 + i, rb = ra + 8;
    float acca = 0.f, accb = 0.f;
    #pragma unroll
    for (int k8 = 0; k8 < 8; k8++){
      uint4 va = *(const uint4*)&sVh[ra*64 + k8*8];
      uint4 vb = *(const uint4*)&sVh[rb*64 + k8*8];
      h2 w0 = uph(sW2h[(k8*4+0)*64 + tx]);
      h2 w1 = uph(sW2h[(k8*4+1)*64 + tx]);
      h2 w2 = uph(sW2h[(k8*4+2)*64 + tx]);
      h2 w3 = uph(sW2h[(k8*4+3)*64 + tx]);
      acca = fdot2(uph(va.x), w0, acca); accb = fdot2(uph(vb.x), w0, accb);
      acca = fdot2(uph(va.y), w1, acca); accb = fdot2(uph(vb.y), w1, accb);
      acca = fdot2(uph(va.z), w2, acca); accb = fdot2(uph(vb.z), w2, accb);
      acca = fdot2(uph(va.w), w3, acca); accb = fdot2(uph(vb.w), w3, accb);
    }
    float ta = fmaxf(acca, 0.f), tb = fmaxf(accb, 0.f);
    if (ra < nrows){ U[(size_t)(node0+ra)*NH + tx] = ta; ls1 += ta; ls2 += ta*ta; }
    if (rb < nrows){ U[(size_t)(node0+rb)*NH + tx] = tb; ls1 += tb; ls2 += tb*tb; }
  }
  __syncthreads();
  sRed[ty*NH + tx] = ls1;
  sRed[(4+ty)*NH + tx] = ls2;
  __syncthreads();
  if (ty == 0){
    float a1 = sRed[tx] + sRed[NH+tx] + sRed[2*NH+tx] + sRed[3*NH+tx];
    float a2 = sRed[4*NH+tx] + sRed[5*NH+tx] + sRed[6*NH+tx] + sRed[7*NH+tx];
    unsafeAtomicAdd(&s1[tx], a1);
    unsafeAtomicAdd(&s2[tx], a2);
  }
}

extern "C" void kernel_launch(void* const* d_in, const int* in_sizes, int n_in,
                              void* d_out, int out_size, void* d_ws, size_t ws_size,
                              hipStream_t stream) {
  const void* x    = d_in[0];
  const int* ei    = (const int*)d_in[1];
  const int* batch = (const int*)d_in[2];
  const void* Wt   = d_in[3];
  const void* bt   = d_in[4];
  const void* g0   = d_in[5];
  const void* b0   = d_in[6];
  const void* W1   = d_in[7];
  const void* W2   = d_in[8];
  const void* gs   = d_in[9];
  const void* bs   = d_in[10];

  u16*  hbuf = (u16*)d_ws;                      // NN*NH f16 (in NN*NH*4-byte slot)
  float* ubuf = (float*)d_ws + (size_t)NN*NH;   // NN*NH f32 (U, then in-place T)
  float* s1   = ubuf + (size_t)NN*NH;           // 64
  float* s2   = s1 + NH;                        // 64 (contiguous after s1)
  float* pad  = s2 + NH;                        // 128 (layout spacer)
  int* starts = (int*)(pad + 2*NH);             // 512
  int* flag   = starts + 512;                   // 64 (padded)
  int* deg    = flag + 64;                      // NN
  int* rowptr = deg + NN;                       // NN+64
  int* cursor = rowptr + NN + 64;               // NN
  int* csr    = cursor + NN;                    // NE
  int* bsum   = csr + NE;                       // 256

  hipMemsetAsync(s1, 0, 2*NH*sizeof(float), stream);
  hipMemsetAsync(deg, 0, NN*sizeof(int), stream);
  k_detect<<<1, 64, 0, stream>>>((const u32*)x, flag);
  k_bounds<<<1, 512, 0, stream>>>(batch, starts);
  k_count<<<(NE+255)/256, 256, 0, stream>>>(ei, deg);
  k_scanA<<<SCAN_B, 256, 0, stream>>>(deg, bsum);
  k_scanB<<<1, 256, 0, stream>>>(bsum);
  k_scanC<<<SCAN_B, 256, 0, stream>>>(deg, bsum, rowptr, cursor);
  k_fill<<<(NE+255)/256, 256, 0, stream>>>(ei, cursor, csr);

  k_transform_f<<<(NN+31)/32, 256, 0, stream>>>((const float*)x, (const float*)Wt, (const float*)bt, ubuf, s1, s2);
  k_embed<<<NG, 256, 0, stream>>>(ubuf, s1, s2, g0, b0, 0, hbuf, 1, starts, flag, d_out, 0);

  for (int l = 0; l < 3; l++){
    k_gather<<<(NN+3)/4, 256, 0, stream>>>(hbuf, rowptr, csr, ubuf, s1);  // also zeros s1/s2
    k_mlp_f<<<(NN+63)/64, 256, 0, stream>>>(ubuf, (const float*)W1, (const float*)W2, l*NH*NH, s1, s2);
    k_embed<<<NG, 256, 0, stream>>>(ubuf, s1, s2, gs, bs, l*NH, hbuf, (l < 2) ? 1 : 0, starts, flag, d_out, l+1);
  }
}

// Round 18
// 440.299 us; speedup vs baseline: 1.2576x; 1.0096x over previous
//
#include <hip/hip_runtime.h>
#include <hip/hip_bf16.h>

#define NN 50000
#define NE 800000
#define NG 500
#define NF 128
#define NH 64
#define SCAN_B ((NN + 255)/256)   // 196

typedef unsigned int u32;
typedef unsigned short u16;
typedef _Float16 h2 __attribute__((ext_vector_type(2)));

__device__ __forceinline__ float bf1(u16 v){ return __uint_as_float(((u32)v) << 16); }

__device__ __forceinline__ float fdot2(h2 a, h2 b, float c){
#if __has_builtin(__builtin_amdgcn_fdot2)
  return __builtin_amdgcn_fdot2(a, b, c, false);
#else
  return c + (float)a.x*(float)b.x + (float)a.y*(float)b.y;
#endif
}
__device__ __forceinline__ u32 pk(float a, float b){
  return __builtin_bit_cast(u32, __builtin_amdgcn_cvt_pkrtz(a, b));
}
__device__ __forceinline__ h2 uph(u32 u){ return __builtin_bit_cast(h2, u); }
__device__ __forceinline__ u16 f16b(float f){ return __builtin_bit_cast(u16, (_Float16)f); }

// decode 8 f16 -> 8 f32
__device__ __forceinline__ void cv8h(uint4 q, float* f){
  h2 v0 = uph(q.x), v1 = uph(q.y), v2 = uph(q.z), v3 = uph(q.w);
  f[0]=(float)v0.x; f[1]=(float)v0.y; f[2]=(float)v1.x; f[3]=(float)v1.y;
  f[4]=(float)v2.x; f[5]=(float)v2.y; f[6]=(float)v3.x; f[7]=(float)v3.y;
}

// ---- dtype probe (f32 inputs proven; kept as output-format hedge)
__global__ void k_detect(const u32* __restrict__ x, int* __restrict__ flag){
  int lane = threadIdx.x;
  u32 w = x[lane];
  u32 lo = w & 0xFFFFu;
  u32 e = (lo >> 7) & 0xFFu;
  bool vote = (e >= 0x60u && e <= 0x8Fu);
  unsigned long long m = __ballot(vote);
  if (lane == 0) flag[0] = (__popcll(m) >= 32) ? 1 : 0;
}

// ---- graph boundaries
__global__ void k_bounds(const int* __restrict__ batch, int* __restrict__ starts){
  int g = threadIdx.x;
  if (g > NG) return;
  int lo = 0, hi = NN;
  while (lo < hi){ int mid = (lo + hi) >> 1; if (batch[mid] < g) lo = mid + 1; else hi = mid; }
  starts[g] = lo;
}

// ---- CSR build: degree count
__global__ __launch_bounds__(256) void k_count(const int* __restrict__ ei, int* __restrict__ deg){
  int e = blockIdx.x*256 + threadIdx.x;
  if (e >= NE) return;
  atomicAdd(&deg[ei[NE + e]], 1);
}

// ---- hierarchical coalesced scan (3 phases)
__global__ __launch_bounds__(256) void k_scanA(const int* __restrict__ deg, int* __restrict__ bsum){
  __shared__ int red[256];
  int t = threadIdx.x;
  int i = blockIdx.x*256 + t;
  red[t] = (i < NN) ? deg[i] : 0;
  __syncthreads();
  for (int off = 128; off > 0; off >>= 1){
    if (t < off) red[t] += red[t+off];
    __syncthreads();
  }
  if (t == 0) bsum[blockIdx.x] = red[0];
}

__global__ __launch_bounds__(256) void k_scanB(int* __restrict__ bsum){
  __shared__ int part[256];
  int t = threadIdx.x;
  int v = (t < SCAN_B) ? bsum[t] : 0;
  part[t] = v;
  __syncthreads();
  for (int off = 1; off < 256; off <<= 1){
    int u = (t >= off) ? part[t-off] : 0;
    __syncthreads();
    part[t] += u;
    __syncthreads();
  }
  if (t < SCAN_B) bsum[t] = part[t] - v;   // exclusive
}

__global__ __launch_bounds__(256) void k_scanC(const int* __restrict__ deg, const int* __restrict__ bsum,
    int* __restrict__ rowptr, int* __restrict__ cursor){
  __shared__ int part[256];
  int t = threadIdx.x;
  int i = blockIdx.x*256 + t;
  int v = (i < NN) ? deg[i] : 0;
  part[t] = v;
  __syncthreads();
  for (int off = 1; off < 256; off <<= 1){
    int u = (t >= off) ? part[t-off] : 0;
    __syncthreads();
    part[t] += u;
    __syncthreads();
  }
  int ex = part[t] - v + bsum[blockIdx.x];
  if (i < NN){ rowptr[i] = ex; cursor[i] = ex; }
  if (blockIdx.x == 0 && t == 0) rowptr[NN] = NE;
}

// ---- CSR fill (R13-proven: 1 edge/thread)
__global__ __launch_bounds__(256) void k_fill(const int* __restrict__ ei,
    int* __restrict__ cursor, int* __restrict__ csr){
  int e = blockIdx.x*256 + threadIdx.x;
  if (e >= NE) return;
  int dst = ei[NE + e];
  int slot = atomicAdd(&cursor[dst], 1);
  csr[slot] = ei[e];
}

// ---- gather (f16 h -> f16 U): 8-slot x 8-chunk + unroll x2; block 0 re-zeros s1/s2
__global__ __launch_bounds__(256) void k_gather(const u16* __restrict__ h,
    const int* __restrict__ rowptr, const int* __restrict__ csr, u16* __restrict__ Uh,
    float* __restrict__ s1){
  if (blockIdx.x == 0 && threadIdx.x < 128) s1[threadIdx.x] = 0.f;  // s1[0:64], s2[64:128]
  int wid = threadIdx.x >> 6, lane = threadIdx.x & 63;
  int node = blockIdx.x*4 + wid;
  if (node >= NN) return;
  int chunk = lane & 7, epar = lane >> 3;
  int beg = rowptr[node], en = rowptr[node+1];
  float acc[8] = {0.f,0.f,0.f,0.f,0.f,0.f,0.f,0.f};
  if (epar == 0){
    uint4 q = *(const uint4*)&h[(size_t)node*NH + chunk*8];
    cv8h(q, acc);
  }
  int j = beg + epar;
  for (; j + 8 < en; j += 16){            // 2 edges in flight per lane
    int src0 = csr[j];
    int src1 = csr[j+8];
    uint4 q0 = *(const uint4*)&h[(size_t)src0*NH + chunk*8];
    uint4 q1 = *(const uint4*)&h[(size_t)src1*NH + chunk*8];
    float f0[8], f1[8];
    cv8h(q0, f0);
    cv8h(q1, f1);
    #pragma unroll
    for (int i = 0; i < 8; i++) acc[i] += f0[i] + f1[i];
  }
  if (j < en){
    int src = csr[j];
    uint4 q = *(const uint4*)&h[(size_t)src*NH + chunk*8];
    float f[8]; cv8h(q, f);
    #pragma unroll
    for (int i = 0; i < 8; i++) acc[i] += f[i];
  }
  #pragma unroll
  for (int i = 0; i < 8; i++){
    acc[i] += __shfl_xor(acc[i], 8);
    acc[i] += __shfl_xor(acc[i], 16);
    acc[i] += __shfl_xor(acc[i], 32);
  }
  if (epar == 0){
    uint4 o;
    o.x = pk(acc[0], acc[1]); o.y = pk(acc[2], acc[3]);
    o.z = pk(acc[4], acc[5]); o.w = pk(acc[6], acc[7]);
    *(uint4*)&Uh[(size_t)node*NH + chunk*8] = o;
  }
}

// ---- transform: LDS-staged x (float4 staging for MLP) + 16-reg weight hoist
__global__ __launch_bounds__(256) void k_transform_f(const float* __restrict__ x,
    const float* __restrict__ Wt, const float* __restrict__ bt,
    float* __restrict__ t, float* __restrict__ s1, float* __restrict__ s2){
  __shared__ u32 sWh[64*64];      // 16 KB: half2(W[2k2][c], W[2k2+1][c]) at [k2][c]
  __shared__ u32 sXh[32*64];      // 8 KB: half2(x[r][2k2], x[r][2k2+1]) at [r][k2]
  __shared__ float sRed[8*NH];
  int tid = threadIdx.x;
  for (int i = tid; i < 1024; i += 256){
    int k2 = i >> 4, c4 = i & 15;
    float4 a = *(const float4*)(Wt + (size_t)(2*k2)*NH + c4*4);
    float4 b = *(const float4*)(Wt + (size_t)(2*k2+1)*NH + c4*4);
    uint4 st;
    st.x = pk(a.x, b.x); st.y = pk(a.y, b.y); st.z = pk(a.z, b.z); st.w = pk(a.w, b.w);
    *(uint4*)&sWh[k2*64 + c4*4] = st;
  }
  int row0 = blockIdx.x*32;
  for (int i = tid; i < 1024; i += 256){   // 4 iters x float4 (16 B): 2x in-flight bytes
    int r = i >> 5, k4 = i & 31;
    int row = row0 + r;
    float4 v;
    if (row < NN) v = *(const float4*)(x + (size_t)row*NF + 4*k4);
    else { v.x=0.f; v.y=0.f; v.z=0.f; v.w=0.f; }
    uint2 p2; p2.x = pk(v.x, v.y); p2.y = pk(v.z, v.w);
    *(uint2*)&sXh[r*64 + k4*2] = p2;
  }
  __syncthreads();
  int tx = tid & 63, ty = tid >> 6;
  float b = bt[tx];
  float acc0[8], acc1[8];
  #pragma unroll
  for (int i = 0; i < 8; i++){ acc0[i] = 0.f; acc1[i] = 0.f; }
  #pragma unroll 1
  for (int ch = 0; ch < 4; ch++){        // 16 k2 per chunk: only 16 wreg live
    u32 wreg[16];
    #pragma unroll
    for (int j = 0; j < 16; j++) wreg[j] = sWh[(ch*16+j)*64 + tx];
    #pragma unroll
    for (int i = 0; i < 8; i++){
      int r = ty*8 + i;
      const uint4* xp = (const uint4*)&sXh[r*64 + ch*16];   // uniform b128 (4 k2 each)
      #pragma unroll
      for (int q = 0; q < 4; q++){
        uint4 xv = xp[q];
        acc0[i] = fdot2(uph(xv.x), uph(wreg[q*4+0]), acc0[i]);
        acc1[i] = fdot2(uph(xv.y), uph(wreg[q*4+1]), acc1[i]);
        acc0[i] = fdot2(uph(xv.z), uph(wreg[q*4+2]), acc0[i]);
        acc1[i] = fdot2(uph(xv.w), uph(wreg[q*4+3]), acc1[i]);
      }
    }
  }
  float ls1 = 0.f, ls2 = 0.f;
  #pragma unroll
  for (int i = 0; i < 8; i++){
    int row = row0 + ty*8 + i;
    float acc = acc0[i] + acc1[i] + b;
    if (row < NN){
      t[(size_t)row*NH + tx] = acc;
      ls1 += acc; ls2 += acc*acc;
    }
  }
  sRed[ty*NH + tx] = ls1;
  sRed[(4+ty)*NH + tx] = ls2;
  __syncthreads();
  if (ty == 0){
    float a1 = sRed[tx] + sRed[NH+tx] + sRed[2*NH+tx] + sRed[3*NH+tx];
    float a2 = sRed[4*NH+tx] + sRed[5*NH+tx] + sRed[6*NH+tx] + sRed[7*NH+tx];
    unsafeAtomicAdd(&s1[tx], a1);
    unsafeAtomicAdd(&s2[tx], a2);
  }
}

// ---- per-graph embed with fused BN-fold; writes h as f16 (gather is sole consumer)
__global__ __launch_bounds__(256) void k_embed(const float* __restrict__ t,
    const float* __restrict__ s1, const float* __restrict__ s2,
    const void* __restrict__ gamma, const void* __restrict__ beta, int ofs,
    u16* __restrict__ h, int write_h,
    const int* __restrict__ starts, const int* __restrict__ flag,
    void* __restrict__ dout, int layer){
  __shared__ float sRed[8*NH];
  int g = blockIdx.x;
  int tx = threadIdx.x & 63, ty = threadIdx.x >> 6;
  int bf = flag[0];
  float gm = bf ? bf1(((const u16*)gamma)[ofs+tx]) : ((const float*)gamma)[ofs+tx];
  float be = bf ? bf1(((const u16*)beta)[ofs+tx])  : ((const float*)beta)[ofs+tx];
  float mean = s1[tx] * (1.f/NN);
  float var  = s2[tx] * (1.f/NN) - mean*mean;
  float rr = rsqrtf(fmaxf(var, 0.f) + 1e-5f);
  float sc = gm * rr;
  float sh = be - mean*sc;
  int st = starts[g], en = starts[g+1];
  float ls1 = 0.f, ls2 = 0.f;
  if (write_h){
    for (int n = st + ty; n < en; n += 4){
      float z = t[(size_t)n*NH + tx] * sc + sh;
      h[(size_t)n*NH + tx] = f16b(z);
      ls1 += z; ls2 += z*z;
    }
  } else {
    for (int n = st + ty; n < en; n += 4){
      float z = t[(size_t)n*NH + tx] * sc + sh;
      ls1 += z; ls2 += z*z;
    }
  }
  sRed[ty*NH + tx] = ls1;
  sRed[(4+ty)*NH + tx] = ls2;
  __syncthreads();
  if (ty == 0){
    float a1 = sRed[tx] + sRed[NH+tx] + sRed[2*NH+tx] + sRed[3*NH+tx];
    float a2 = sRed[4*NH+tx] + sRed[5*NH+tx] + sRed[6*NH+tx] + sRed[7*NH+tx];
    int cnt = en - st;
    float inv = 1.f / (float)max(cnt, 1);
    float m = a1 * inv;
    float vv = a2 * inv - m*m;
    float s = sqrtf(fmaxf(vv, 0.f));
    size_t eidx = ((size_t)layer*NG + g)*NH + tx;
    size_t sidx = (size_t)4*NG*NH + eidx;
    if (bf){
      ((__hip_bfloat16*)dout)[eidx] = __float2bfloat16(m);
      ((__hip_bfloat16*)dout)[sidx] = __float2bfloat16(s);
    } else {
      ((float*)dout)[eidx] = m;
      ((float*)dout)[sidx] = s;
    }
  }
}

// ---- MLP: f16 U input (plain uint4 staging) + LDS weight reads + fdot2, row-paired
__global__ __launch_bounds__(256) void k_mlp_f(const u16* __restrict__ Uh, float* __restrict__ T,
    const float* __restrict__ W1, const float* __restrict__ W2, int wofs,
    float* __restrict__ s1, float* __restrict__ s2){
  __shared__ u32 sW1h[32*64];   // 8 KB
  __shared__ u32 sW2h[32*64];   // 8 KB
  __shared__ u16 sUh[64*64];    // 8 KB
  __shared__ u16 sVh[64*64];    // 8 KB
  __shared__ float sRed[8*NH];  // 2 KB
  int tid = threadIdx.x;
  for (int i = tid; i < 512; i += 256){
    int k2 = i >> 4, c4 = i & 15;
    float4 a1 = *(const float4*)(W1 + wofs + (size_t)(2*k2)*NH + c4*4);
    float4 b1 = *(const float4*)(W1 + wofs + (size_t)(2*k2+1)*NH + c4*4);
    uint4 s;
    s.x = pk(a1.x, b1.x); s.y = pk(a1.y, b1.y); s.z = pk(a1.z, b1.z); s.w = pk(a1.w, b1.w);
    *(uint4*)&sW1h[k2*64 + c4*4] = s;
    float4 a2 = *(const float4*)(W2 + wofs + (size_t)(2*k2)*NH + c4*4);
    float4 b2 = *(const float4*)(W2 + wofs + (size_t)(2*k2+1)*NH + c4*4);
    uint4 s2v;
    s2v.x = pk(a2.x, b2.x); s2v.y = pk(a2.y, b2.y); s2v.z = pk(a2.z, b2.z); s2v.w = pk(a2.w, b2.w);
    *(uint4*)&sW2h[k2*64 + c4*4] = s2v;
  }
  int node0 = blockIdx.x*64;
  int nrows = min(64, NN - node0);
  for (int i = tid; i < 512; i += 256){   // 2 iters x uint4: direct f16 copy
    int r = i >> 3, g = i & 7;
    uint4 q;
    if (r < nrows) q = *(const uint4*)&Uh[(size_t)(node0+r)*NH + g*8];
    else { q.x=0; q.y=0; q.z=0; q.w=0; }
    *(uint4*)&sUh[r*64 + g*8] = q;
  }
  __syncthreads();
  int tx = tid & 63, ty = tid >> 6;
  // phase A: V = relu(U @ W1)
  for (int i = 0; i < 8; i++){
    int ra = ty*16 + i, rb = ra + 8;
    float acca = 0.f, accb = 0.f;
    #pragma unroll
    for (int k8 = 0; k8 < 8; k8++){
      uint4 ua = *(const uint4*)&sUh[ra*64 + k8*8];
      uint4 ub = *(const uint4*)&sUh[rb*64 + k8*8];
      h2 w0 = uph(sW1h[(k8*4+0)*64 + tx]);
      h2 w1 = uph(sW1h[(k8*4+1)*64 + tx]);
      h2 w2 = uph(sW1h[(k8*4+2)*64 + tx]);
      h2 w3 = uph(sW1h[(k8*4+3)*64 + tx]);
      acca = fdot2(uph(ua.x), w0, acca); accb = fdot2(uph(ub.x), w0, accb);
      acca = fdot2(uph(ua.y), w1, acca); accb = fdot2(uph(ub.y), w1, accb);
      acca = fdot2(uph(ua.z), w2, acca); accb = fdot2(uph(ub.z), w2, accb);
      acca = fdot2(uph(ua.w), w3, acca); accb = fdot2(uph(ub.w), w3, accb);
    }
    sVh[ra*64 + tx] = f16b(fmaxf(acca, 0.f));
    sVh[rb*64 + tx] = f16b(fmaxf(accb, 0.f));
  }
  __syncthreads();
  // phase B: T = relu(V @ W2)
  float ls1 = 0.f, ls2 = 0.f;
  for (int i = 0; i < 8; i++){
    int ra = ty*16 + i, rb = ra + 8;
    float acca = 0.f, accb = 0.f;
    #pragma unroll
    for (int k8 = 0; k8 < 8; k8++){
      uint4 va = *(const uint4*)&sVh[ra*64 + k8*8];
      uint4 vb = *(const uint4*)&sVh[rb*64 + k8*8];
      h2 w0 = uph(sW2h[(k8*4+0)*64 + tx]);
      h2 w1 = uph(sW2h[(k8*4+1)*64 + tx]);
      h2 w2 = uph(sW2h[(k8*4+2)*64 + tx]);
      h2 w3 = uph(sW2h[(k8*4+3)*64 + tx]);
      acca = fdot2(uph(va.x), w0, acca); accb = fdot2(uph(vb.x), w0, accb);
      acca = fdot2(uph(va.y), w1, acca); accb = fdot2(uph(vb.y), w1, accb);
      acca = fdot2(uph(va.z), w2, acca); accb = fdot2(uph(vb.z), w2, accb);
      acca = fdot2(uph(va.w), w3, acca); accb = fdot2(uph(vb.w), w3, accb);
    }
    float ta = fmaxf(acca, 0.f), tb = fmaxf(accb, 0.f);
    if (ra < nrows){ T[(size_t)(node0+ra)*NH + tx] = ta; ls1 += ta; ls2 += ta*ta; }
    if (rb < nrows){ T[(size_t)(node0+rb)*NH + tx] = tb; ls1 += tb; ls2 += tb*tb; }
  }
  __syncthreads();
  sRed[ty*NH + tx] = ls1;
  sRed[(4+ty)*NH + tx] = ls2;
  __syncthreads();
  if (ty == 0){
    float a1 = sRed[tx] + sRed[NH+tx] + sRed[2*NH+tx] + sRed[3*NH+tx];
    float a2 = sRed[4*NH+tx] + sRed[5*NH+tx] + sRed[6*NH+tx] + sRed[7*NH+tx];
    unsafeAtomicAdd(&s1[tx], a1);
    unsafeAtomicAdd(&s2[tx], a2);
  }
}

extern "C" void kernel_launch(void* const* d_in, const int* in_sizes, int n_in,
                              void* d_out, int out_size, void* d_ws, size_t ws_size,
                              hipStream_t stream) {
  const void* x    = d_in[0];
  const int* ei    = (const int*)d_in[1];
  const int* batch = (const int*)d_in[2];
  const void* Wt   = d_in[3];
  const void* bt   = d_in[4];
  const void* g0   = d_in[5];
  const void* b0   = d_in[6];
  const void* W1   = d_in[7];
  const void* W2   = d_in[8];
  const void* gs   = d_in[9];
  const void* bs   = d_in[10];

  u16*  hbuf = (u16*)d_ws;                      // NN*NH f16 (first half of 12.8 MB slot)
  u16*  uh16 = hbuf + (size_t)NN*NH;            // NN*NH f16 (second half of same slot)
  float* ubuf = (float*)d_ws + (size_t)NN*NH;   // NN*NH f32 (transform t / mlp T output)
  float* s1   = ubuf + (size_t)NN*NH;           // 64
  float* s2   = s1 + NH;                        // 64 (contiguous after s1)
  float* pad  = s2 + NH;                        // 128 (layout spacer)
  int* starts = (int*)(pad + 2*NH);             // 512
  int* flag   = starts + 512;                   // 64 (padded)
  int* deg    = flag + 64;                      // NN
  int* rowptr = deg + NN;                       // NN+64
  int* cursor = rowptr + NN + 64;               // NN
  int* csr    = cursor + NN;                    // NE
  int* bsum   = csr + NE;                       // 256

  hipMemsetAsync(s1, 0, 2*NH*sizeof(float), stream);
  hipMemsetAsync(deg, 0, NN*sizeof(int), stream);
  k_detect<<<1, 64, 0, stream>>>((const u32*)x, flag);
  k_bounds<<<1, 512, 0, stream>>>(batch, starts);
  k_count<<<(NE+255)/256, 256, 0, stream>>>(ei, deg);
  k_scanA<<<SCAN_B, 256, 0, stream>>>(deg, bsum);
  k_scanB<<<1, 256, 0, stream>>>(bsum);
  k_scanC<<<SCAN_B, 256, 0, stream>>>(deg, bsum, rowptr, cursor);
  k_fill<<<(NE+255)/256, 256, 0, stream>>>(ei, cursor, csr);

  k_transform_f<<<(NN+31)/32, 256, 0, stream>>>((const float*)x, (const float*)Wt, (const float*)bt, ubuf, s1, s2);
  k_embed<<<NG, 256, 0, stream>>>(ubuf, s1, s2, g0, b0, 0, hbuf, 1, starts, flag, d_out, 0);

  for (int l = 0; l < 3; l++){
    k_gather<<<(NN+3)/4, 256, 0, stream>>>(hbuf, rowptr, csr, uh16, s1);  // also zeros s1/s2
    k_mlp_f<<<(NN+63)/64, 256, 0, stream>>>(uh16, ubuf, (const float*)W1, (const float*)W2, l*NH*NH, s1, s2);
    k_embed<<<NG, 256, 0, stream>>>(ubuf, s1, s2, gs, bs, l*NH, hbuf, (l < 2) ? 1 : 0, starts, flag, d_out, l+1);
  }
}

// Round 19
// 435.154 us; speedup vs baseline: 1.2724x; 1.0118x over previous
//
#include <hip/hip_runtime.h>
#include <hip/hip_bf16.h>

#define NN 50000
#define NE 800000
#define NG 500
#define NF 128
#define NH 64
#define SCAN_B ((NN + 255)/256)   // 196

typedef unsigned int u32;
typedef unsigned short u16;
typedef _Float16 h2 __attribute__((ext_vector_type(2)));

__device__ __forceinline__ float bf1(u16 v){ return __uint_as_float(((u32)v) << 16); }
__device__ __forceinline__ float h1(u16 v){ return (float)__builtin_bit_cast(_Float16, v); }

__device__ __forceinline__ float fdot2(h2 a, h2 b, float c){
#if __has_builtin(__builtin_amdgcn_fdot2)
  return __builtin_amdgcn_fdot2(a, b, c, false);
#else
  return c + (float)a.x*(float)b.x + (float)a.y*(float)b.y;
#endif
}
__device__ __forceinline__ u32 pk(float a, float b){
  return __builtin_bit_cast(u32, __builtin_amdgcn_cvt_pkrtz(a, b));
}
__device__ __forceinline__ h2 uph(u32 u){ return __builtin_bit_cast(h2, u); }
__device__ __forceinline__ u16 f16b(float f){ return __builtin_bit_cast(u16, (_Float16)f); }

// decode 8 f16 -> 8 f32
__device__ __forceinline__ void cv8h(uint4 q, float* f){
  h2 v0 = uph(q.x), v1 = uph(q.y), v2 = uph(q.z), v3 = uph(q.w);
  f[0]=(float)v0.x; f[1]=(float)v0.y; f[2]=(float)v1.x; f[3]=(float)v1.y;
  f[4]=(float)v2.x; f[5]=(float)v2.y; f[6]=(float)v3.x; f[7]=(float)v3.y;
}

// ---- dtype probe (f32 inputs proven; kept as output-format hedge)
__global__ void k_detect(const u32* __restrict__ x, int* __restrict__ flag){
  int lane = threadIdx.x;
  u32 w = x[lane];
  u32 lo = w & 0xFFFFu;
  u32 e = (lo >> 7) & 0xFFu;
  bool vote = (e >= 0x60u && e <= 0x8Fu);
  unsigned long long m = __ballot(vote);
  if (lane == 0) flag[0] = (__popcll(m) >= 32) ? 1 : 0;
}

// ---- graph boundaries
__global__ void k_bounds(const int* __restrict__ batch, int* __restrict__ starts){
  int g = threadIdx.x;
  if (g > NG) return;
  int lo = 0, hi = NN;
  while (lo < hi){ int mid = (lo + hi) >> 1; if (batch[mid] < g) lo = mid + 1; else hi = mid; }
  starts[g] = lo;
}

// ---- CSR build: degree count
__global__ __launch_bounds__(256) void k_count(const int* __restrict__ ei, int* __restrict__ deg){
  int e = blockIdx.x*256 + threadIdx.x;
  if (e >= NE) return;
  atomicAdd(&deg[ei[NE + e]], 1);
}

// ---- hierarchical coalesced scan (3 phases)
__global__ __launch_bounds__(256) void k_scanA(const int* __restrict__ deg, int* __restrict__ bsum){
  __shared__ int red[256];
  int t = threadIdx.x;
  int i = blockIdx.x*256 + t;
  red[t] = (i < NN) ? deg[i] : 0;
  __syncthreads();
  for (int off = 128; off > 0; off >>= 1){
    if (t < off) red[t] += red[t+off];
    __syncthreads();
  }
  if (t == 0) bsum[blockIdx.x] = red[0];
}

__global__ __launch_bounds__(256) void k_scanB(int* __restrict__ bsum){
  __shared__ int part[256];
  int t = threadIdx.x;
  int v = (t < SCAN_B) ? bsum[t] : 0;
  part[t] = v;
  __syncthreads();
  for (int off = 1; off < 256; off <<= 1){
    int u = (t >= off) ? part[t-off] : 0;
    __syncthreads();
    part[t] += u;
    __syncthreads();
  }
  if (t < SCAN_B) bsum[t] = part[t] - v;   // exclusive
}

__global__ __launch_bounds__(256) void k_scanC(const int* __restrict__ deg, const int* __restrict__ bsum,
    int* __restrict__ rowptr, int* __restrict__ cursor){
  __shared__ int part[256];
  int t = threadIdx.x;
  int i = blockIdx.x*256 + t;
  int v = (i < NN) ? deg[i] : 0;
  part[t] = v;
  __syncthreads();
  for (int off = 1; off < 256; off <<= 1){
    int u = (t >= off) ? part[t-off] : 0;
    __syncthreads();
    part[t] += u;
    __syncthreads();
  }
  int ex = part[t] - v + bsum[blockIdx.x];
  if (i < NN){ rowptr[i] = ex; cursor[i] = ex; }
  if (blockIdx.x == 0 && t == 0) rowptr[NN] = NE;
}

// ---- CSR fill (R13-proven: 1 edge/thread)
__global__ __launch_bounds__(256) void k_fill(const int* __restrict__ ei,
    int* __restrict__ cursor, int* __restrict__ csr){
  int e = blockIdx.x*256 + threadIdx.x;
  if (e >= NE) return;
  int dst = ei[NE + e];
  int slot = atomicAdd(&cursor[dst], 1);
  csr[slot] = ei[e];
}

// ---- gather (f16 h -> f16 U): 8-slot x 8-chunk + unroll x2; block 0 re-zeros s1/s2
__global__ __launch_bounds__(256) void k_gather(const u16* __restrict__ h,
    const int* __restrict__ rowptr, const int* __restrict__ csr, u16* __restrict__ Uh,
    float* __restrict__ s1){
  if (blockIdx.x == 0 && threadIdx.x < 128) s1[threadIdx.x] = 0.f;  // s1[0:64], s2[64:128]
  int wid = threadIdx.x >> 6, lane = threadIdx.x & 63;
  int node = blockIdx.x*4 + wid;
  if (node >= NN) return;
  int chunk = lane & 7, epar = lane >> 3;
  int beg = rowptr[node], en = rowptr[node+1];
  float acc[8] = {0.f,0.f,0.f,0.f,0.f,0.f,0.f,0.f};
  if (epar == 0){
    uint4 q = *(const uint4*)&h[(size_t)node*NH + chunk*8];
    cv8h(q, acc);
  }
  int j = beg + epar;
  for (; j + 8 < en; j += 16){            // 2 edges in flight per lane
    int src0 = csr[j];
    int src1 = csr[j+8];
    uint4 q0 = *(const uint4*)&h[(size_t)src0*NH + chunk*8];
    uint4 q1 = *(const uint4*)&h[(size_t)src1*NH + chunk*8];
    float f0[8], f1[8];
    cv8h(q0, f0);
    cv8h(q1, f1);
    #pragma unroll
    for (int i = 0; i < 8; i++) acc[i] += f0[i] + f1[i];
  }
  if (j < en){
    int src = csr[j];
    uint4 q = *(const uint4*)&h[(size_t)src*NH + chunk*8];
    float f[8]; cv8h(q, f);
    #pragma unroll
    for (int i = 0; i < 8; i++) acc[i] += f[i];
  }
  #pragma unroll
  for (int i = 0; i < 8; i++){
    acc[i] += __shfl_xor(acc[i], 8);
    acc[i] += __shfl_xor(acc[i], 16);
    acc[i] += __shfl_xor(acc[i], 32);
  }
  if (epar == 0){
    uint4 o;
    o.x = pk(acc[0], acc[1]); o.y = pk(acc[2], acc[3]);
    o.z = pk(acc[4], acc[5]); o.w = pk(acc[6], acc[7]);
    *(uint4*)&Uh[(size_t)node*NH + chunk*8] = o;
  }
}

// ---- transform: LDS-staged x + 16-reg weight hoist; writes t as f16
__global__ __launch_bounds__(256) void k_transform_f(const float* __restrict__ x,
    const float* __restrict__ Wt, const float* __restrict__ bt,
    u16* __restrict__ th, float* __restrict__ s1, float* __restrict__ s2){
  __shared__ u32 sWh[64*64];      // 16 KB: half2(W[2k2][c], W[2k2+1][c]) at [k2][c]
  __shared__ u32 sXh[32*64];      // 8 KB: half2(x[r][2k2], x[r][2k2+1]) at [r][k2]
  __shared__ float sRed[8*NH];
  int tid = threadIdx.x;
  for (int i = tid; i < 1024; i += 256){
    int k2 = i >> 4, c4 = i & 15;
    float4 a = *(const float4*)(Wt + (size_t)(2*k2)*NH + c4*4);
    float4 b = *(const float4*)(Wt + (size_t)(2*k2+1)*NH + c4*4);
    uint4 st;
    st.x = pk(a.x, b.x); st.y = pk(a.y, b.y); st.z = pk(a.z, b.z); st.w = pk(a.w, b.w);
    *(uint4*)&sWh[k2*64 + c4*4] = st;
  }
  int row0 = blockIdx.x*32;
  for (int i = tid; i < 1024; i += 256){   // 4 iters x float4 (16 B)
    int r = i >> 5, k4 = i & 31;
    int row = row0 + r;
    float4 v;
    if (row < NN) v = *(const float4*)(x + (size_t)row*NF + 4*k4);
    else { v.x=0.f; v.y=0.f; v.z=0.f; v.w=0.f; }
    uint2 p2; p2.x = pk(v.x, v.y); p2.y = pk(v.z, v.w);
    *(uint2*)&sXh[r*64 + k4*2] = p2;
  }
  __syncthreads();
  int tx = tid & 63, ty = tid >> 6;
  float b = bt[tx];
  float acc0[8], acc1[8];
  #pragma unroll
  for (int i = 0; i < 8; i++){ acc0[i] = 0.f; acc1[i] = 0.f; }
  #pragma unroll 1
  for (int ch = 0; ch < 4; ch++){        // 16 k2 per chunk: only 16 wreg live
    u32 wreg[16];
    #pragma unroll
    for (int j = 0; j < 16; j++) wreg[j] = sWh[(ch*16+j)*64 + tx];
    #pragma unroll
    for (int i = 0; i < 8; i++){
      int r = ty*8 + i;
      const uint4* xp = (const uint4*)&sXh[r*64 + ch*16];   // uniform b128 (4 k2 each)
      #pragma unroll
      for (int q = 0; q < 4; q++){
        uint4 xv = xp[q];
        acc0[i] = fdot2(uph(xv.x), uph(wreg[q*4+0]), acc0[i]);
        acc1[i] = fdot2(uph(xv.y), uph(wreg[q*4+1]), acc1[i]);
        acc0[i] = fdot2(uph(xv.z), uph(wreg[q*4+2]), acc0[i]);
        acc1[i] = fdot2(uph(xv.w), uph(wreg[q*4+3]), acc1[i]);
      }
    }
  }
  float ls1 = 0.f, ls2 = 0.f;
  #pragma unroll
  for (int i = 0; i < 8; i++){
    int row = row0 + ty*8 + i;
    float acc = acc0[i] + acc1[i] + b;
    if (row < NN){
      th[(size_t)row*NH + tx] = f16b(acc);
      ls1 += acc; ls2 += acc*acc;
    }
  }
  sRed[ty*NH + tx] = ls1;
  sRed[(4+ty)*NH + tx] = ls2;
  __syncthreads();
  if (ty == 0){
    float a1 = sRed[tx] + sRed[NH+tx] + sRed[2*NH+tx] + sRed[3*NH+tx];
    float a2 = sRed[4*NH+tx] + sRed[5*NH+tx] + sRed[6*NH+tx] + sRed[7*NH+tx];
    unsafeAtomicAdd(&s1[tx], a1);
    unsafeAtomicAdd(&s2[tx], a2);
  }
}

// ---- per-graph embed with fused BN-fold; reads f16 t, writes h as f16
__global__ __launch_bounds__(256) void k_embed(const u16* __restrict__ t,
    const float* __restrict__ s1, const float* __restrict__ s2,
    const void* __restrict__ gamma, const void* __restrict__ beta, int ofs,
    u16* __restrict__ h, int write_h,
    const int* __restrict__ starts, const int* __restrict__ flag,
    void* __restrict__ dout, int layer){
  __shared__ float sRed[8*NH];
  int g = blockIdx.x;
  int tx = threadIdx.x & 63, ty = threadIdx.x >> 6;
  int bf = flag[0];
  float gm = bf ? bf1(((const u16*)gamma)[ofs+tx]) : ((const float*)gamma)[ofs+tx];
  float be = bf ? bf1(((const u16*)beta)[ofs+tx])  : ((const float*)beta)[ofs+tx];
  float mean = s1[tx] * (1.f/NN);
  float var  = s2[tx] * (1.f/NN) - mean*mean;
  float rr = rsqrtf(fmaxf(var, 0.f) + 1e-5f);
  float sc = gm * rr;
  float sh = be - mean*sc;
  int st = starts[g], en = starts[g+1];
  float ls1 = 0.f, ls2 = 0.f;
  if (write_h){
    for (int n = st + ty; n < en; n += 4){
      float z = h1(t[(size_t)n*NH + tx]) * sc + sh;
      h[(size_t)n*NH + tx] = f16b(z);
      ls1 += z; ls2 += z*z;
    }
  } else {
    for (int n = st + ty; n < en; n += 4){
      float z = h1(t[(size_t)n*NH + tx]) * sc + sh;
      ls1 += z; ls2 += z*z;
    }
  }
  sRed[ty*NH + tx] = ls1;
  sRed[(4+ty)*NH + tx] = ls2;
  __syncthreads();
  if (ty == 0){
    float a1 = sRed[tx] + sRed[NH+tx] + sRed[2*NH+tx] + sRed[3*NH+tx];
    float a2 = sRed[4*NH+tx] + sRed[5*NH+tx] + sRed[6*NH+tx] + sRed[7*NH+tx];
    int cnt = en - st;
    float inv = 1.f / (float)max(cnt, 1);
    float m = a1 * inv;
    float vv = a2 * inv - m*m;
    float s = sqrtf(fmaxf(vv, 0.f));
    size_t eidx = ((size_t)layer*NG + g)*NH + tx;
    size_t sidx = (size_t)4*NG*NH + eidx;
    if (bf){
      ((__hip_bfloat16*)dout)[eidx] = __float2bfloat16(m);
      ((__hip_bfloat16*)dout)[sidx] = __float2bfloat16(s);
    } else {
      ((float*)dout)[eidx] = m;
      ((float*)dout)[sidx] = s;
    }
  }
}

// ---- MLP: f16 U input + LDS weight reads + fdot2, row-paired; writes T as f16
__global__ __launch_bounds__(256) void k_mlp_f(const u16* __restrict__ Uh, u16* __restrict__ Th,
    const float* __restrict__ W1, const float* __restrict__ W2, int wofs,
    float* __restrict__ s1, float* __restrict__ s2){
  __shared__ u32 sW1h[32*64];   // 8 KB
  __shared__ u32 sW2h[32*64];   // 8 KB
  __shared__ u16 sUh[64*64];    // 8 KB
  __shared__ u16 sVh[64*64];    // 8 KB
  __shared__ float sRed[8*NH];  // 2 KB
  int tid = threadIdx.x;
  for (int i = tid; i < 512; i += 256){
    int k2 = i >> 4, c4 = i & 15;
    float4 a1 = *(const float4*)(W1 + wofs + (size_t)(2*k2)*NH + c4*4);
    float4 b1 = *(const float4*)(W1 + wofs + (size_t)(2*k2+1)*NH + c4*4);
    uint4 s;
    s.x = pk(a1.x, b1.x); s.y = pk(a1.y, b1.y); s.z = pk(a1.z, b1.z); s.w = pk(a1.w, b1.w);
    *(uint4*)&sW1h[k2*64 + c4*4] = s;
    float4 a2 = *(const float4*)(W2 + wofs + (size_t)(2*k2)*NH + c4*4);
    float4 b2 = *(const float4*)(W2 + wofs + (size_t)(2*k2+1)*NH + c4*4);
    uint4 s2v;
    s2v.x = pk(a2.x, b2.x); s2v.y = pk(a2.y, b2.y); s2v.z = pk(a2.z, b2.z); s2v.w = pk(a2.w, b2.w);
    *(uint4*)&sW2h[k2*64 + c4*4] = s2v;
  }
  int node0 = blockIdx.x*64;
  int nrows = min(64, NN - node0);
  for (int i = tid; i < 512; i += 256){   // 2 iters x uint4: direct f16 copy
    int r = i >> 3, g = i & 7;
    uint4 q;
    if (r < nrows) q = *(const uint4*)&Uh[(size_t)(node0+r)*NH + g*8];
    else { q.x=0; q.y=0; q.z=0; q.w=0; }
    *(uint4*)&sUh[r*64 + g*8] = q;
  }
  __syncthreads();
  int tx = tid & 63, ty = tid >> 6;
  // phase A: V = relu(U @ W1)
  for (int i = 0; i < 8; i++){
    int ra = ty*16 + i, rb = ra + 8;
    float acca = 0.f, accb = 0.f;
    #pragma unroll
    for (int k8 = 0; k8 < 8; k8++){
      uint4 ua = *(const uint4*)&sUh[ra*64 + k8*8];
      uint4 ub = *(const uint4*)&sUh[rb*64 + k8*8];
      h2 w0 = uph(sW1h[(k8*4+0)*64 + tx]);
      h2 w1 = uph(sW1h[(k8*4+1)*64 + tx]);
      h2 w2 = uph(sW1h[(k8*4+2)*64 + tx]);
      h2 w3 = uph(sW1h[(k8*4+3)*64 + tx]);
      acca = fdot2(uph(ua.x), w0, acca); accb = fdot2(uph(ub.x), w0, accb);
      acca = fdot2(uph(ua.y), w1, acca); accb = fdot2(uph(ub.y), w1, accb);
      acca = fdot2(uph(ua.z), w2, acca); accb = fdot2(uph(ub.z), w2, accb);
      acca = fdot2(uph(ua.w), w3, acca); accb = fdot2(uph(ub.w), w3, accb);
    }
    sVh[ra*64 + tx] = f16b(fmaxf(acca, 0.f));
    sVh[rb*64 + tx] = f16b(fmaxf(accb, 0.f));
  }
  __syncthreads();
  // phase B: T = relu(V @ W2)
  float ls1 = 0.f, ls2 = 0.f;
  for (int i = 0; i < 8; i++){
    int ra = ty*16 + i, rb = ra + 8;
    float acca = 0.f, accb = 0.f;
    #pragma unroll
    for (int k8 = 0; k8 < 8; k8++){
      uint4 va = *(const uint4*)&sVh[ra*64 + k8*8];
      uint4 vb = *(const uint4*)&sVh[rb*64 + k8*8];
      h2 w0 = uph(sW2h[(k8*4+0)*64 + tx]);
      h2 w1 = uph(sW2h[(k8*4+1)*64 + tx]);
      h2 w2 = uph(sW2h[(k8*4+2)*64 + tx]);
      h2 w3 = uph(sW2h[(k8*4+3)*64 + tx]);
      acca = fdot2(uph(va.x), w0, acca); accb = fdot2(uph(vb.x), w0, accb);
      acca = fdot2(uph(va.y), w1, acca); accb = fdot2(uph(vb.y), w1, accb);
      acca = fdot2(uph(va.z), w2, acca); accb = fdot2(uph(vb.z), w2, accb);
      acca = fdot2(uph(va.w), w3, acca); accb = fdot2(uph(vb.w), w3, accb);
    }
    float ta = fmaxf(acca, 0.f), tb = fmaxf(accb, 0.f);
    if (ra < nrows){ Th[(size_t)(node0+ra)*NH + tx] = f16b(ta); ls1 += ta; ls2 += ta*ta; }
    if (rb < nrows){ Th[(size_t)(node0+rb)*NH + tx] = f16b(tb); ls1 += tb; ls2 += tb*tb; }
  }
  __syncthreads();
  sRed[ty*NH + tx] = ls1;
  sRed[(4+ty)*NH + tx] = ls2;
  __syncthreads();
  if (ty == 0){
    float a1 = sRed[tx] + sRed[NH+tx] + sRed[2*NH+tx] + sRed[3*NH+tx];
    float a2 = sRed[4*NH+tx] + sRed[5*NH+tx] + sRed[6*NH+tx] + sRed[7*NH+tx];
    unsafeAtomicAdd(&s1[tx], a1);
    unsafeAtomicAdd(&s2[tx], a2);
  }
}

extern "C" void kernel_launch(void* const* d_in, const int* in_sizes, int n_in,
                              void* d_out, int out_size, void* d_ws, size_t ws_size,
                              hipStream_t stream) {
  const void* x    = d_in[0];
  const int* ei    = (const int*)d_in[1];
  const int* batch = (const int*)d_in[2];
  const void* Wt   = d_in[3];
  const void* bt   = d_in[4];
  const void* g0   = d_in[5];
  const void* b0   = d_in[6];
  const void* W1   = d_in[7];
  const void* W2   = d_in[8];
  const void* gs   = d_in[9];
  const void* bs   = d_in[10];

  u16*  hbuf = (u16*)d_ws;                      // NN*NH f16
  u16*  uh16 = hbuf + (size_t)NN*NH;            // NN*NH f16
  u16*  tb16 = uh16 + (size_t)NN*NH;            // NN*NH f16 (t, f16 end-to-end)
  float* s1   = (float*)d_ws + 2*(size_t)NN*NH; // 64 (after 2 f32-slots worth of f16)
  float* s2   = s1 + NH;                        // 64
  float* pad  = s2 + NH;                        // 128 (layout spacer)
  int* starts = (int*)(pad + 2*NH);             // 512
  int* flag   = starts + 512;                   // 64 (padded)
  int* deg    = flag + 64;                      // NN
  int* rowptr = deg + NN;                       // NN+64
  int* cursor = rowptr + NN + 64;               // NN
  int* csr    = cursor + NN;                    // NE
  int* bsum   = csr + NE;                       // 256

  hipMemsetAsync(s1, 0, 2*NH*sizeof(float), stream);
  hipMemsetAsync(deg, 0, NN*sizeof(int), stream);
  k_detect<<<1, 64, 0, stream>>>((const u32*)x, flag);
  k_bounds<<<1, 512, 0, stream>>>(batch, starts);
  k_count<<<(NE+255)/256, 256, 0, stream>>>(ei, deg);
  k_scanA<<<SCAN_B, 256, 0, stream>>>(deg, bsum);
  k_scanB<<<1, 256, 0, stream>>>(bsum);
  k_scanC<<<SCAN_B, 256, 0, stream>>>(deg, bsum, rowptr, cursor);
  k_fill<<<(NE+255)/256, 256, 0, stream>>>(ei, cursor, csr);

  k_transform_f<<<(NN+31)/32, 256, 0, stream>>>((const float*)x, (const float*)Wt, (const float*)bt, tb16, s1, s2);
  k_embed<<<NG, 256, 0, stream>>>(tb16, s1, s2, g0, b0, 0, hbuf, 1, starts, flag, d_out, 0);

  for (int l = 0; l < 3; l++){
    k_gather<<<(NN+3)/4, 256, 0, stream>>>(hbuf, rowptr, csr, uh16, s1);  // also zeros s1/s2
    k_mlp_f<<<(NN+63)/64, 256, 0, stream>>>(uh16, tb16, (const float*)W1, (const float*)W2, l*NH*NH, s1, s2);
    k_embed<<<NG, 256, 0, stream>>>(tb16, s1, s2, gs, bs, l*NH, hbuf, (l < 2) ? 1 : 0, starts, flag, d_out, l+1);
  }
}